// Round 6
// baseline (440.697 us; speedup 1.0000x reference)
//
#include <hip/hip_runtime.h>

// DenseGINConv fused: out = mask * ( relu( ((1+eps)*x + adj@x) @ W1 + b1 ) @ W2 + b2 )
// B=64, N=1024, F_IN=64, F_HID=128, F_OUT=64, fp32 in/out.
//
// Round 6: barrier-free phase A + all-MFMA MLP (mfma_f32_32x32x16_bf16,
// m74/m101-verified layouts throughout).
//  - adj A-frags loaded DIRECTLY from global (no LDS, no barriers in the
//    64-step k-loop); bf16 convert in-reg; B-frags from pre-packed xt (ws).
//  - W1/W2 pre-packed to B-frag layout (same unit convention as xt, proven).
//  - h and h1 round-trip LDS as bf16 rows (stride 136 hw = 272 B) = A-frag
//    readable with the proven ds_read pattern. Only 2 barriers total.
//  - 35 KB LDS, __launch_bounds__(256,4) -> 4 blocks/CU, all 1024 resident.

#define N_    1024
#define FIN   64
#define FHID  128
#define FOUT  64
#define HROW  136          // halfword row stride for hf/h1f (128 used + 8 pad)

typedef __attribute__((ext_vector_type(16))) float f32x16;
typedef __attribute__((ext_vector_type(8)))  short s16x8;

__device__ inline short f2bf(float f) {
    union { float f; unsigned int u; } v; v.f = f;
    unsigned int r = v.u + 0x7fffu + ((v.u >> 16) & 1u);   // RNE
    return (short)(r >> 16);
}

// ---------------- pre-kernel 1: pack x -> bf16 B-fragment-major (proven r5) ----------
// group g = (b*64 + ks)*2 + ng ; unit u = n*2 + half ; elem e:
//   xt[g*64+u][e] = bf16( x[b][ks*16 + 8*half + e][ng*32 + n] )
__global__ __launch_bounds__(256) void xt_pack(const float* __restrict__ x,
                                               s16x8* __restrict__ xt)
{
    const int g  = blockIdx.x * 256 + threadIdx.x;   // 0 .. 262143
    const int n  = g & 31;
    const int ng = (g >> 5) & 1;
    const int ks = (g >> 6) & 63;
    const int b  = g >> 12;
    const int f  = ng * 32 + n;

    s16x8 u0, u1;
    #pragma unroll
    for (int k = 0; k < 8; ++k)
        u0[k] = f2bf(x[(size_t)(b * N_ + ks * 16 + k) * FIN + f]);
    #pragma unroll
    for (int k = 0; k < 8; ++k)
        u1[k] = f2bf(x[(size_t)(b * N_ + ks * 16 + 8 + k) * FIN + f]);
    xt[2 * g]     = u0;
    xt[2 * g + 1] = u1;
}

// ---------------- pre-kernel 2: pack W1, W2 -> B-frag layout ----------------
// W1: unit (ks*4+ng)*64 + u  (ks 0..3, ng 0..3): W1[(16ks+8half+e)*FHID + 32ng+n]
// W2: unit (ks*2+ng)*64 + u  (ks 0..7, ng 0..1): W2[(16ks+8half+e)*FOUT + 32ng+n]
__global__ __launch_bounds__(256) void w_pack(const float* __restrict__ W1,
                                              const float* __restrict__ W2,
                                              s16x8* __restrict__ w1f,
                                              s16x8* __restrict__ w2f)
{
    const int g = blockIdx.x * 256 + threadIdx.x;    // 0..2047
    const int u    = g & 63;
    const int n    = u >> 1;
    const int half = u & 1;
    if (g < 1024) {
        const int ng = (g >> 6) & 3;
        const int ks = g >> 8;
        s16x8 fr;
        #pragma unroll
        for (int e = 0; e < 8; ++e)
            fr[e] = f2bf(W1[(16 * ks + 8 * half + e) * FHID + 32 * ng + n]);
        w1f[g] = fr;
    } else {
        const int g2 = g - 1024;
        const int ng = (g2 >> 6) & 1;
        const int ks = g2 >> 7;
        s16x8 fr;
        #pragma unroll
        for (int e = 0; e < 8; ++e)
            fr[e] = f2bf(W2[(16 * ks + 8 * half + e) * FOUT + 32 * ng + n]);
        w2f[g2] = fr;
    }
}

// ---------------- main kernel ----------------
__global__ __launch_bounds__(256, 4) void gin_main(
    const float* __restrict__ x, const float* __restrict__ adj,
    const int* __restrict__ mask, const float* __restrict__ b1,
    const float* __restrict__ b2, const float* __restrict__ epsp,
    const s16x8* __restrict__ xt, const s16x8* __restrict__ w1f,
    const s16x8* __restrict__ w2f, float* __restrict__ out)
{
    __shared__ unsigned short hf_hw[64 * HROW];    // h  tile bf16 (17408 B)
    __shared__ unsigned short h1f_hw[64 * HROW];   // h1 tile bf16 (17408 B)
    __shared__ int mask_s[64];

    const int t    = threadIdx.x;
    const int lane = t & 63;
    const int w    = t >> 6;
    const int b    = blockIdx.x >> 4;
    const int i0   = (blockIdx.x & 15) * 64;

    const int l31  = lane & 31;
    const int half = lane >> 5;
    const int mrow = (w & 1) * 32;
    const int ncol = (w >> 1) * 32;
    const int bfl  = l31 * 2 + half;

    if (t < 64) mask_s[t] = mask[b * N_ + i0 + t];

    // ---------------- Phase A: agg = adj @ x, barrier-free ----------------
    // A-frag: lane reads adj row (i0+mrow+l31), cols 16s + 8*half + 0..7.
    const float* ap = adj + (size_t)b * N_ * N_
                          + (size_t)(i0 + mrow + l31) * N_ + 8 * half;
    const s16x8* xb0 = xt + ((size_t)(b * 64) * 2 + (w >> 1)) * 64 + bfl;

    f32x16 acc;
    #pragma unroll
    for (int r = 0; r < 16; ++r) acc[r] = 0.f;

    #pragma unroll 8
    for (int s = 0; s < 64; ++s) {
        const float4 u = *reinterpret_cast<const float4*>(ap + 16 * s);
        const float4 v = *reinterpret_cast<const float4*>(ap + 16 * s + 4);
        const s16x8  bf = xb0[(size_t)s * 128];   // (bgbase + s*2)*64 + bfl
        s16x8 afr;
        afr[0] = f2bf(u.x); afr[1] = f2bf(u.y); afr[2] = f2bf(u.z); afr[3] = f2bf(u.w);
        afr[4] = f2bf(v.x); afr[5] = f2bf(v.y); afr[6] = f2bf(v.z); afr[7] = f2bf(v.w);
        acc = __builtin_amdgcn_mfma_f32_32x32x16_bf16(afr, bf, acc, 0, 0, 0);
    }

    // epilogue: h = (1+eps)*x + agg -> hf (bf16, A-frag-readable rows)
    {
        const float se = 1.0f + epsp[0];
        const int col = ncol + l31;
        #pragma unroll
        for (int reg = 0; reg < 16; ++reg) {
            const int row = mrow + (reg & 3) + 8 * (reg >> 2) + 4 * half;
            const float xv = x[(size_t)(b * N_ + i0 + row) * FIN + col];
            hf_hw[row * HROW + col] = (unsigned short)f2bf(acc[reg] + se * xv);
        }
    }
    __syncthreads();

    // ---------------- Phase B: h1 = relu(h @ W1 + b1), MFMA ----------------
    // wave w: rows mrow..mrow+31, n-groups ngB = 2*(w>>1)+g, g=0,1
    {
        f32x16 acc2[2];
        #pragma unroll
        for (int g = 0; g < 2; ++g) {
            const float b1v = b1[32 * (2 * (w >> 1) + g) + l31];
            #pragma unroll
            for (int r = 0; r < 16; ++r) acc2[g][r] = b1v;
        }
        #pragma unroll
        for (int s = 0; s < 4; ++s) {
            const s16x8 a = *reinterpret_cast<const s16x8*>(
                &hf_hw[(mrow + l31) * HROW + 16 * s + 8 * half]);
            #pragma unroll
            for (int g = 0; g < 2; ++g) {
                const int ngB = 2 * (w >> 1) + g;
                const s16x8 bw = w1f[(s * 4 + ngB) * 64 + bfl];
                acc2[g] = __builtin_amdgcn_mfma_f32_32x32x16_bf16(a, bw, acc2[g], 0, 0, 0);
            }
        }
        #pragma unroll
        for (int g = 0; g < 2; ++g) {
            const int col = 32 * (2 * (w >> 1) + g) + l31;
            #pragma unroll
            for (int reg = 0; reg < 16; ++reg) {
                const int row = mrow + (reg & 3) + 8 * (reg >> 2) + 4 * half;
                h1f_hw[row * HROW + col] = (unsigned short)f2bf(fmaxf(acc2[g][reg], 0.f));
            }
        }
    }
    __syncthreads();

    // ---------------- Phase C: out = mask * (h1 @ W2 + b2), MFMA ----------------
    {
        f32x16 acc3;
        const float b2v = b2[ncol + l31];
        #pragma unroll
        for (int r = 0; r < 16; ++r) acc3[r] = b2v;

        #pragma unroll
        for (int s = 0; s < 8; ++s) {
            const s16x8 a = *reinterpret_cast<const s16x8*>(
                &h1f_hw[(mrow + l31) * HROW + 16 * s + 8 * half]);
            const s16x8 bw = w2f[(s * 2 + (w >> 1)) * 64 + bfl];
            acc3 = __builtin_amdgcn_mfma_f32_32x32x16_bf16(a, bw, acc3, 0, 0, 0);
        }

        const int col = ncol + l31;
        #pragma unroll
        for (int reg = 0; reg < 16; ++reg) {
            const int row = mrow + (reg & 3) + 8 * (reg >> 2) + 4 * half;
            const float o = mask_s[row] ? acc3[reg] : 0.f;
            out[(size_t)(b * N_ + i0 + row) * FOUT + col] = o;
        }
    }
}

extern "C" void kernel_launch(void* const* d_in, const int* in_sizes, int n_in,
                              void* d_out, int out_size, void* d_ws, size_t ws_size,
                              hipStream_t stream) {
    const float* x    = (const float*)d_in[0];
    const float* adj  = (const float*)d_in[1];
    const int*   mask = (const int*)  d_in[2];
    const float* W1   = (const float*)d_in[3];
    const float* b1   = (const float*)d_in[4];
    const float* W2   = (const float*)d_in[5];
    const float* b2   = (const float*)d_in[6];
    const float* eps  = (const float*)d_in[7];
    float* out = (float*)d_out;

    s16x8* xt  = (s16x8*)d_ws;           // 524288 units = 8 MB
    s16x8* w1f = xt + 524288;            // 1024 units = 16 KB
    s16x8* w2f = w1f + 1024;             // 1024 units = 16 KB

    xt_pack<<<dim3(1024), dim3(256), 0, stream>>>(x, xt);
    w_pack<<<dim3(8), dim3(256), 0, stream>>>(W1, W2, w1f, w2f);
    gin_main<<<dim3(64 * 16), dim3(256), 0, stream>>>(x, adj, mask, b1, b2, eps,
                                                      xt, w1f, w2f, out);
}